// Round 7
// baseline (378.446 us; speedup 1.0000x reference)
//
#include <hip/hip_runtime.h>
#include <math.h>

#define BATCH   2
#define SLEN    2048
#define DMODEL  1024
#define NHEAD   16
#define DHEAD   64
#define DOUT    2048
#define MROWS   (BATCH * SLEN)   // 4096
#define NSPLIT  2
#define KSPAN   (SLEN / NSPLIT)  // 1024
#define QSCALE  0.1803368801f    // 0.125 * log2(e); folded into Q projection

typedef short bf16x8 __attribute__((ext_vector_type(8)));
typedef float floatx4 __attribute__((ext_vector_type(4)));

static __device__ __forceinline__ unsigned short f2bf(float f) {
  unsigned u = __float_as_uint(f);
  u += 0x7fff + ((u >> 16) & 1);
  return (unsigned short)(u >> 16);
}
static __device__ __forceinline__ float bf2f(unsigned short s) {
  return __uint_as_float(((unsigned)s) << 16);
}
// pack two f32 -> two bf16 (RNE). gfx950 has V_CVT_PK_BF16_F32 (1 inst).
static __device__ __forceinline__ unsigned int pk_bf16(float a, float b) {
#if defined(__gfx950__) && __has_builtin(__builtin_amdgcn_cvt_pk_bf16_f32)
  typedef __bf16 bf2_t __attribute__((ext_vector_type(2)));
  bf2_t r = __builtin_amdgcn_cvt_pk_bf16_f32(a, b);
  return __builtin_bit_cast(unsigned int, r);
#else
  return ((unsigned)f2bf(b) << 16) | f2bf(a);
#endif
}
static __device__ __forceinline__ floatx4 mfma16(bf16x8 a, bf16x8 b, floatx4 c) {
  return __builtin_amdgcn_mfma_f32_16x16x32_bf16(a, b, c, 0, 0, 0);
}
// async global->LDS, 16B per lane; LDS dest = wave-uniform base + lane*16
static __device__ __forceinline__ void gll16(const void* g, void* l) {
  __builtin_amdgcn_global_load_lds(
      (const __attribute__((address_space(1))) unsigned int*)g,
      (__attribute__((address_space(3))) unsigned int*)l, 16, 0, 0);
}

// ============ fused f32 -> bf16 convert for q,k,v (one launch) ==============
__global__ __launch_bounds__(256) void conv_all_k(
    const float* __restrict__ q, const float* __restrict__ k,
    const float* __restrict__ v, unsigned short* __restrict__ qb,
    unsigned short* __restrict__ kb, unsigned short* __restrict__ vb) {
  int i = blockIdx.x * 256 + threadIdx.x;  // vec8 units; total 2M
  const float* src;
  unsigned short* dst;
  if (i < (1 << 19)) { src = q; dst = qb; }
  else if (i < (1 << 20)) { src = k; dst = kb; i -= 1 << 19; }
  else { src = v; dst = vb; i -= 1 << 20; }
  const float4 a = ((const float4*)src)[i * 2];
  const float4 b = ((const float4*)src)[i * 2 + 1];
  uint4 u;
  u.x = pk_bf16(a.x, a.y);
  u.y = pk_bf16(a.z, a.w);
  u.z = pk_bf16(b.x, b.y);
  u.w = pk_bf16(b.z, b.w);
  ((uint4*)dst)[i] = u;
}

// ==== fused W[K][N] f32 -> WT[N][K] bf16 for all four weights (one launch) ==
__global__ __launch_bounds__(256) void wtrans_all_k(
    const float* __restrict__ Wq, const float* __restrict__ Wk,
    const float* __restrict__ Wv, const float* __restrict__ Wfc,
    unsigned short* __restrict__ WqT, unsigned short* __restrict__ WkT,
    unsigned short* __restrict__ WvT, unsigned short* __restrict__ WfcT) {
  __shared__ float T[32][33];
  int id = blockIdx.x;
  const float* W;
  unsigned short* WT;
  int K, N;
  if (id < 1024)      { W = Wq;  WT = WqT;  K = 1024; N = 1024; }
  else if (id < 2048) { W = Wk;  WT = WkT;  K = 1024; N = 1024; id -= 1024; }
  else if (id < 4096) { W = Wv;  WT = WvT;  K = 2048; N = 1024; id -= 2048; }
  else                { W = Wfc; WT = WfcT; K = 1024; N = 2048; id -= 4096; }
  const int ntn = N / 32;
  const int n0 = (id % ntn) * 32, k0 = (id / ntn) * 32;
  const int t = threadIdx.x;
  {
    const int r = t >> 3, c4 = (t & 7) * 4;
    const float4 w = *(const float4*)(W + (size_t)(k0 + r) * N + n0 + c4);
    T[r][c4 + 0] = w.x; T[r][c4 + 1] = w.y; T[r][c4 + 2] = w.z; T[r][c4 + 3] = w.w;
  }
  __syncthreads();
  {
    const int n = t >> 3, k4 = (t & 7) * 4;
    uint2 u;
    u.x = pk_bf16(T[k4 + 0][n], T[k4 + 1][n]);
    u.y = pk_bf16(T[k4 + 2][n], T[k4 + 3][n]);
    *(uint2*)(WT + (size_t)(n0 + n) * K + k0 + k4) = u;
  }
}

// === MFMA GEMM body: C = A[M][K] x BT[N][K]^T + bias, all scaled by `scale`.
// 128x128 tile (m97 structure), BK=64, 256 thr = 4 waves, wave = 64x64 (4x4).
// global_load_lds staging into XOR-swizzled LDS (chunk g at g^(row&7)).
// MODE: 0 = bf16 row-major, 1 = f32 row-major, 2 = bf16 transposed C^T[N][M].
template <int MODE>
static __device__ __forceinline__ void gemm_body(
    const unsigned short* __restrict__ A, const unsigned short* __restrict__ BT,
    const float* __restrict__ bias, void* __restrict__ C, int M, int K, int N,
    int row0, int col0, float scale) {
  __shared__ unsigned short As[128 * 64];
  __shared__ unsigned short Bs[128 * 64];
  const int t = threadIdx.x;
  const int w = t >> 6, l = t & 63, quad = l >> 4, lq = l & 15;
  const int wm = (w >> 1) * 64, wn = (w & 1) * 64;

  const unsigned short *aS[4], *bS[4];
#pragma unroll
  for (int jj = 0; jj < 4; jj++) {
    const int r = (w * 4 + jj) * 8 + (l >> 3);
    const int c = ((l & 7) ^ (r & 7)) << 3;
    aS[jj] = A + (size_t)(row0 + r) * K + c;
    bS[jj] = BT + (size_t)(col0 + r) * K + c;
  }

  floatx4 acc[4][4];
#pragma unroll
  for (int i = 0; i < 4; i++)
#pragma unroll
    for (int j = 0; j < 4; j++) acc[i][j] = (floatx4){0.f, 0.f, 0.f, 0.f};

  for (int kt = 0; kt < K; kt += 64) {
#pragma unroll
    for (int jj = 0; jj < 4; jj++) {
      gll16(aS[jj] + kt, As + (w * 4 + jj) * 512);
      gll16(bS[jj] + kt, Bs + (w * 4 + jj) * 512);
    }
    __syncthreads();

    bf16x8 af[4][2], bfr[4][2];
#pragma unroll
    for (int ti = 0; ti < 4; ti++) {
      const int m = wm + ti * 16 + lq;
      const int n = wn + ti * 16 + lq;
#pragma unroll
      for (int h = 0; h < 2; h++) {
        af[ti][h] = *(const bf16x8*)(As + m * 64 + (((h * 4 + quad) ^ (m & 7)) << 3));
        bfr[ti][h] = *(const bf16x8*)(Bs + n * 64 + (((h * 4 + quad) ^ (n & 7)) << 3));
      }
    }
#pragma unroll
    for (int ti = 0; ti < 4; ti++)
#pragma unroll
      for (int tj = 0; tj < 4; tj++) {
        acc[ti][tj] = mfma16(af[ti][0], bfr[tj][0], acc[ti][tj]);
        acc[ti][tj] = mfma16(af[ti][1], bfr[tj][1], acc[ti][tj]);
      }
    __syncthreads();
  }

#pragma unroll
  for (int tj = 0; tj < 4; tj++) {
    const int col = col0 + wn + tj * 16 + lq;
    const float bv = bias[col];
    if (MODE == 2) {
#pragma unroll
      for (int ti = 0; ti < 4; ti++) {
        uint2 u;
        u.x = pk_bf16((acc[ti][tj][0] + bv) * scale, (acc[ti][tj][1] + bv) * scale);
        u.y = pk_bf16((acc[ti][tj][2] + bv) * scale, (acc[ti][tj][3] + bv) * scale);
        *(uint2*)((unsigned short*)C + (size_t)col * M + row0 + wm + ti * 16 +
                  quad * 4) = u;
      }
    } else {
#pragma unroll
      for (int ti = 0; ti < 4; ti++)
#pragma unroll
        for (int r = 0; r < 4; r++) {
          const int row = row0 + wm + ti * 16 + quad * 4 + r;
          const float vv = (acc[ti][tj][r] + bv) * scale;
          if (MODE == 1)
            ((float*)C)[(size_t)row * N + col] = vv;
          else
            ((unsigned short*)C)[(size_t)row * N + col] = f2bf(vv);
        }
    }
  }
}

// all three projections in one launch (blockIdx.z selects; block-uniform).
// Q projection pre-scaled by 0.125*log2(e) so softmax uses exp2(z + bias).
__global__ __launch_bounds__(256) void proj_k(
    const unsigned short* qb, const unsigned short* kb, const unsigned short* vb,
    const unsigned short* WqT, const unsigned short* WkT,
    const unsigned short* WvT, const float* bq, const float* bk,
    const float* bv, unsigned short* Qp, unsigned short* Kp,
    unsigned short* VT) {
  const int z = blockIdx.z;
  if (z == 2)
    gemm_body<2>(vb, WvT, bv, VT, MROWS, 2 * DMODEL, DMODEL,
                 blockIdx.y * 128, blockIdx.x * 128, 1.f);
  else if (z == 1)
    gemm_body<0>(kb, WkT, bk, Kp, MROWS, DMODEL, DMODEL,
                 blockIdx.y * 128, blockIdx.x * 128, 1.f);
  else
    gemm_body<0>(qb, WqT, bq, Qp, MROWS, DMODEL, DMODEL,
                 blockIdx.y * 128, blockIdx.x * 128, QSCALE);
}
__global__ __launch_bounds__(256) void fc_k(
    const unsigned short* att, const unsigned short* WfcT, const float* bfc,
    float* out) {
  gemm_body<1>(att, WfcT, bfc, out, MROWS, DMODEL, DOUT,
               blockIdx.y * 128, blockIdx.x * 128, 1.f);
}

// ============== Flash attention (m=0), S^T = K·Q^T formulation ==============
// Block = (b, h, split, q-tile128), 4 waves, wave owns 32 q (2 sets of 16).
// K/V tile 64 staged once per iter feeds 32 wave-MFMAs (2x barrier amortize).
__global__ __launch_bounds__(256) void flash_mfma_k(
    const unsigned short* __restrict__ Qp, const unsigned short* __restrict__ Kp,
    const unsigned short* __restrict__ VT, const int* __restrict__ mask,
    unsigned short* __restrict__ Opart, float* __restrict__ Lpart) {
  __shared__ unsigned short Ks[64 * 64];     // [kk][d], XOR-swizzled 16B chunks
  __shared__ unsigned short Vs[64 * 64];     // [d][kk], XOR-swizzled
  __shared__ unsigned short Ps[4][32 * 68];  // per-wave [q_local][kk], stride 68
  __shared__ float biasL[KSPAN];             // 4 KB: mask ? 0 : -inf
  const int t = threadIdx.x;
  const int w = t >> 6, l = t & 63, quad = l >> 4, lq = l & 15;
  const int q0 = blockIdx.x * 128;
  const int h = blockIdx.y >> 1, split = blockIdx.y & 1;
  const int b = blockIdx.z;

  for (int i = t; i < KSPAN; i += 256)
    biasL[i] = mask[b * SLEN + split * KSPAN + i] ? 0.f : -INFINITY;

  // Q fragments: 2 sets of 16 q rows each (B-operand of S^T MFMA)
  bf16x8 aq[2][2];
#pragma unroll
  for (int s = 0; s < 2; s++) {
    const unsigned short* qptr =
        Qp + (size_t)(b * SLEN + q0 + w * 32 + s * 16 + lq) * DMODEL + h * 64;
    aq[s][0] = *(const bf16x8*)(qptr + quad * 8);
    aq[s][1] = *(const bf16x8*)(qptr + 32 + quad * 8);
  }

  int krow[2], kchunk[2];
#pragma unroll
  for (int jj = 0; jj < 2; jj++) {
    krow[jj] = (w * 2 + jj) * 8 + (l >> 3);
    kchunk[jj] = (l & 7) ^ (krow[jj] & 7);
  }
  const unsigned short* Kbase = Kp + (size_t)b * SLEN * DMODEL + h * 64;
  const unsigned short* Vbase = VT + (size_t)h * 64 * MROWS + b * SLEN;

  floatx4 acc_o[2][4];
#pragma unroll
  for (int s = 0; s < 2; s++)
#pragma unroll
    for (int dj = 0; dj < 4; dj++) acc_o[s][dj] = (floatx4){0.f, 0.f, 0.f, 0.f};
  float lsum[2] = {0.f, 0.f};
  unsigned short* PsW = &Ps[w][0];

  for (int k0s = 0; k0s < KSPAN; k0s += 64) {
    const int k0 = split * KSPAN + k0s;
    __syncthreads();  // also covers biasL visibility on first iter
#pragma unroll
    for (int jj = 0; jj < 2; jj++) {
      const int inst = w * 2 + jj;
      gll16(Kbase + (size_t)(k0 + krow[jj]) * DMODEL + kchunk[jj] * 8,
            Ks + inst * 512);
      gll16(Vbase + (size_t)krow[jj] * MROWS + k0 + kchunk[jj] * 8,
            Vs + inst * 512);
    }
    __syncthreads();

    // S^T tiles: rows kk = ti*16 + quad*4 + r, col q = w*32 + s*16 + lq
#pragma unroll
    for (int ti = 0; ti < 4; ti++) {
      const int kk = ti * 16 + lq;
      const bf16x8 bk0 = *(const bf16x8*)(Ks + kk * 64 + ((quad ^ (kk & 7)) << 3));
      const bf16x8 bk1 =
          *(const bf16x8*)(Ks + kk * 64 + (((4 + quad) ^ (kk & 7)) << 3));
      const float4 bb = *(const float4*)&biasL[k0s + ti * 16 + quad * 4];
#pragma unroll
      for (int s = 0; s < 2; s++) {
        floatx4 z = (floatx4){0.f, 0.f, 0.f, 0.f};
        z = mfma16(bk0, aq[s][0], z);
        z = mfma16(bk1, aq[s][1], z);
        const float e0 = exp2f(z[0] + bb.x);
        const float e1 = exp2f(z[1] + bb.y);
        const float e2 = exp2f(z[2] + bb.z);
        const float e3 = exp2f(z[3] + bb.w);
        lsum[s] += (e0 + e1) + (e2 + e3);
        uint2 pk;
        pk.x = pk_bf16(e0, e1);
        pk.y = pk_bf16(e2, e3);
        *(uint2*)(PsW + (s * 16 + lq) * 68 + ti * 16 + quad * 4) = pk;
      }
    }
    __asm__ __volatile__("" ::: "memory");  // order Ps writes before reads
#pragma unroll
    for (int s = 0; s < 2; s++) {
      const bf16x8 ap0 = *(const bf16x8*)(PsW + (s * 16 + lq) * 68 + quad * 8);
      const bf16x8 ap1 =
          *(const bf16x8*)(PsW + (s * 16 + lq) * 68 + 32 + quad * 8);
#pragma unroll
      for (int dj = 0; dj < 4; dj++) {
        const int d = dj * 16 + lq;
        const bf16x8 bv0 = *(const bf16x8*)(Vs + d * 64 + ((quad ^ (d & 7)) << 3));
        const bf16x8 bv1 =
            *(const bf16x8*)(Vs + d * 64 + (((4 + quad) ^ (d & 7)) << 3));
        acc_o[s][dj] = mfma16(ap0, bv0, acc_o[s][dj]);
        acc_o[s][dj] = mfma16(ap1, bv1, acc_o[s][dj]);
      }
    }
  }

#pragma unroll
  for (int s = 0; s < 2; s++) {
    float v = lsum[s];
    v += __shfl_xor(v, 16);
    v += __shfl_xor(v, 32);
    lsum[s] = v;
  }

  const size_t obase =
      (((size_t)split * BATCH + b) * NHEAD + h) * SLEN + q0 + w * 32;
#pragma unroll
  for (int s = 0; s < 2; s++) {
#pragma unroll
    for (int dj = 0; dj < 4; dj++)
#pragma unroll
      for (int r = 0; r < 4; r++)
        Opart[(obase + s * 16 + quad * 4 + r) * DHEAD + dj * 16 + lq] =
            f2bf(acc_o[s][dj][r]);
    if (quad == 0) Lpart[obase + s * 16 + lq] = lsum[s];
  }
}

// ======= combine split partials: att = (O0+O1)/(l0+l1), lbuf = l0+l1 ========
__global__ __launch_bounds__(256) void combine_k(
    const unsigned short* __restrict__ Opart, const float* __restrict__ Lpart,
    unsigned short* __restrict__ att, float* __restrict__ lbuf) {
  const int gid = blockIdx.x * 256 + threadIdx.x;
  const int row = gid >> 3;
  const int d8 = (gid & 7) * 8;
  const float l0 = Lpart[row];
  const float l1 = Lpart[(size_t)BATCH * NHEAD * SLEN + row];
  const float lt = l0 + l1;
  const float il = (lt > 0.f) ? 1.f / lt : 0.f;
  const bf16x8 o0 = *(const bf16x8*)(Opart + (size_t)row * DHEAD + d8);
  const bf16x8 o1 = *(const bf16x8*)(Opart + (size_t)(BATCH * NHEAD * SLEN) * DHEAD +
                                     (size_t)row * DHEAD + d8);
  const int b = row >> 15, hh = (row >> 11) & 15, q = row & 2047;
  unsigned short* dst = att + (size_t)(b * SLEN + q) * DMODEL + hh * 64 + d8;
  float vv[8];
#pragma unroll
  for (int j = 0; j < 8; j++)
    vv[j] = (bf2f((unsigned short)o0[j]) + bf2f((unsigned short)o1[j])) * il;
  uint4 u;
  u.x = pk_bf16(vv[0], vv[1]);
  u.y = pk_bf16(vv[2], vv[3]);
  u.z = pk_bf16(vv[4], vv[5]);
  u.w = pk_bf16(vv[6], vv[7]);
  *(uint4*)dst = u;
  if ((gid & 7) == 0) lbuf[row] = lt;
}

// ======= attn_avg[b,q,k] = (1/H) sum_h exp2(z_h(q,k)+bias) / l[b,h,q] =======
// il (1/l) for all heads in LDS; 2 heads staged per barrier round.
__global__ __launch_bounds__(256) void attn_avg_mfma_k(
    const unsigned short* __restrict__ Qp, const unsigned short* __restrict__ Kp,
    const float* __restrict__ lbuf, const int* __restrict__ mask,
    float* __restrict__ aout) {
  __shared__ unsigned short Ks[2][64 * 64];  // XOR-swizzled, 2 heads
  __shared__ float ilL[NHEAD * 64];          // 4 KB
  const int t = threadIdx.x;
  const int w = t >> 6, l = t & 63, quad = l >> 4, lq = l & 15;
  const int k0 = blockIdx.x * 64, q0 = blockIdx.y * 64, b = blockIdx.z;

  for (int i = t; i < NHEAD * 64; i += 256) {
    const float lv = lbuf[(b * NHEAD + (i >> 6)) * SLEN + q0 + (i & 63)];
    ilL[i] = (lv > 0.f) ? 1.f / lv : 0.f;
  }
  float bb[4];
#pragma unroll
  for (int ti = 0; ti < 4; ti++)
    bb[ti] = mask[b * SLEN + k0 + ti * 16 + lq] ? 0.f : -INFINITY;

  floatx4 acc[4];
#pragma unroll
  for (int ti = 0; ti < 4; ti++) acc[ti] = (floatx4){0.f, 0.f, 0.f, 0.f};

  int krow[2], kchunk[2];
#pragma unroll
  for (int jj = 0; jj < 2; jj++) {
    krow[jj] = (w * 2 + jj) * 8 + (l >> 3);
    kchunk[jj] = (l & 7) ^ (krow[jj] & 7);
  }
  const unsigned short* Kbase = Kp + (size_t)(b * SLEN + k0) * DMODEL;
  const unsigned short* qbase =
      Qp + (size_t)(b * SLEN + q0 + w * 16 + lq) * DMODEL;

  for (int hp = 0; hp < NHEAD; hp += 2) {
    __syncthreads();  // also covers ilL visibility on first iter
#pragma unroll
    for (int p = 0; p < 2; p++)
#pragma unroll
      for (int jj = 0; jj < 2; jj++)
        gll16(Kbase + (size_t)krow[jj] * DMODEL + (hp + p) * 64 + kchunk[jj] * 8,
              Ks[p] + (w * 2 + jj) * 512);
    __syncthreads();

#pragma unroll
    for (int p = 0; p < 2; p++) {
      const int h = hp + p;
      const bf16x8 aq0 = *(const bf16x8*)(qbase + h * 64 + quad * 8);
      const bf16x8 aq1 = *(const bf16x8*)(qbase + h * 64 + 32 + quad * 8);
      const float4 il4 = *(const float4*)&ilL[h * 64 + w * 16 + quad * 4];
      const float ila[4] = {il4.x, il4.y, il4.z, il4.w};
#pragma unroll
      for (int ti = 0; ti < 4; ti++) {
        const int kk = ti * 16 + lq;
        const bf16x8 bk0 =
            *(const bf16x8*)(Ks[p] + kk * 64 + ((quad ^ (kk & 7)) << 3));
        const bf16x8 bk1 =
            *(const bf16x8*)(Ks[p] + kk * 64 + (((4 + quad) ^ (kk & 7)) << 3));
        floatx4 z = (floatx4){0.f, 0.f, 0.f, 0.f};
        z = mfma16(aq0, bk0, z);
        z = mfma16(aq1, bk1, z);
#pragma unroll
        for (int r = 0; r < 4; r++)
          acc[ti][r] = fmaf(exp2f(z[r] + bb[ti]), ila[r], acc[ti][r]);
      }
    }
  }
  const float ih = 1.f / NHEAD;
#pragma unroll
  for (int ti = 0; ti < 4; ti++)
#pragma unroll
    for (int r = 0; r < 4; r++)
      aout[(size_t)(b * SLEN + q0 + w * 16 + quad * 4 + r) * SLEN + k0 +
           ti * 16 + lq] = acc[ti][r] * ih;
}

extern "C" void kernel_launch(void* const* d_in, const int* in_sizes, int n_in,
                              void* d_out, int out_size, void* d_ws, size_t ws_size,
                              hipStream_t stream) {
  const float* q   = (const float*)d_in[0];
  const float* k   = (const float*)d_in[1];
  const float* v   = (const float*)d_in[2];
  const float* Wq  = (const float*)d_in[3];
  const float* bq  = (const float*)d_in[4];
  const float* Wk  = (const float*)d_in[5];
  const float* bk  = (const float*)d_in[6];
  const float* Wv  = (const float*)d_in[7];
  const float* bv  = (const float*)d_in[8];
  const float* Wfc = (const float*)d_in[9];
  const float* bfc = (const float*)d_in[10];
  const int* mask  = (const int*)d_in[11];

  float* out      = (float*)d_out;                 // [B,S,2D] = 33.5 MB
  float* attn_avg = out + (size_t)MROWS * DOUT;    // [B,S,S]  = 33.5 MB

  // d_out `out` region scratch (dead before the FC writes it):
  // phase 1: qb/kb/vb bf16 (33.5 MB); phase 2: Opart bf16 16 MB + Lpart 512 KB.
  unsigned short* qb = (unsigned short*)d_out;
  unsigned short* kb = qb + (1u << 22);
  unsigned short* vb = kb + (1u << 22);
  unsigned short* Opart = (unsigned short*)d_out;
  float* Lpart = (float*)((char*)d_out + (size_t)NSPLIT * BATCH * NHEAD * SLEN * DHEAD * 2);

  // ws (bf16 elems): WqT 1M | WkT 1M | WvT 2M | WfcT 2M | Qp 4M | Kp 4M |
  // VT 4M | att 4M | lbuf f32 64K
  unsigned short* wsb  = (unsigned short*)d_ws;
  unsigned short* WqT  = wsb;
  unsigned short* WkT  = wsb + (1u << 20);
  unsigned short* WvT  = wsb + (2u << 20);
  unsigned short* WfcT = wsb + (4u << 20);
  unsigned short* Qp   = wsb + (6u << 20);
  unsigned short* Kp   = Qp + (1u << 22);
  unsigned short* VT   = Kp + (1u << 22);
  unsigned short* att  = VT + (1u << 22);
  float* lbuf = (float*)(att + (1u << 22));

  // 0) converts + weight transposes (fused launches)
  conv_all_k<<<dim3(8192), dim3(256), 0, stream>>>(q, k, v, qb, kb, vb);
  wtrans_all_k<<<dim3(6144), dim3(256), 0, stream>>>(Wq, Wk, Wv, Wfc,
                                                     WqT, WkT, WvT, WfcT);
  // 1) Q+K+V projections in one launch (768 blocks, 128x128 tiles)
  proj_k<<<dim3(DMODEL / 128, MROWS / 128, 3), dim3(256), 0, stream>>>(
      qb, kb, vb, WqT, WkT, WvT, bq, bk, bv, Qp, Kp, VT);
  // 2) flash attention (S^T form, q-tile 128, k-split x2) -> Opart/Lpart
  flash_mfma_k<<<dim3(SLEN / 128, NHEAD * NSPLIT, BATCH), dim3(256), 0, stream>>>(
      Qp, Kp, VT, mask, Opart, Lpart);
  // 2b) combine -> att (bf16) + lbuf
  combine_k<<<dim3(BATCH * NHEAD * SLEN * DHEAD / 8 / 256), dim3(256), 0, stream>>>(
      Opart, Lpart, att, lbuf);
  // 3) head-averaged attention map (2 heads per staging round)
  attn_avg_mfma_k<<<dim3(SLEN / 64, SLEN / 64, BATCH), dim3(256), 0, stream>>>(
      Qp, Kp, lbuf, mask, attn_avg);
  // 4) output FC (128x128 tiles, 512 blocks)
  fc_k<<<dim3(DOUT / 128, MROWS / 128), dim3(256), 0, stream>>>(
      att, WfcT, bfc, out);
}